// Round 1
// 134.478 us; speedup vs baseline: 1.0164x; 1.0164x over previous
//
#include <hip/hip_runtime.h>

// ElectronGNN on MI355X (gfx950).  Inputs float32, output float32.
// Round 9: occupancy round — 2 blocks/CU.
//   512 blocks x 256 threads (4 waves), 1 batch/block.
//   Dynamic LDS 67,584 B: single 32KB weight buffer + xb + zst.
//   2 blocks/CU (was 1): co-resident blocks are barrier-independent, so one
//   block's MFMA/VALU fills the other's barrier/waitcnt stalls.
//   Single-buffered weights: per phase {stg_ld(next) -> compute(cur) ->
//   barrier -> stg_st -> barrier}.  Global->reg prefetch still overlaps the
//   MFMA work; only the tiny ds_write (8 x b128/wave) is serialized.
// z B-frags: per-lane v_pk_mul_f16 recompute (r4/r7-proven).  zst wave-private.
// d_ws: 491,520 B (r7-proven size, unchanged).

typedef unsigned short u16;
typedef unsigned int u32;
typedef __attribute__((ext_vector_type(8))) short short8;
typedef __attribute__((ext_vector_type(4))) float f32x4;
typedef __attribute__((ext_vector_type(4))) u32 u32x4;
typedef _Float16 h2 __attribute__((ext_vector_type(2)));

__device__ __forceinline__ u16 f2h(float f){ return __builtin_bit_cast(u16, (_Float16)f); }
__device__ __forceinline__ float h2f(u16 a){ return (float)__builtin_bit_cast(_Float16, a); }

__device__ __forceinline__ short8 rbf8(float dd){
  short8 a;
#pragma unroll
  for (int f = 0; f < 8; f++){
    float u = dd - (4.0f/7.0f)*(float)f;
    a[f] = (short)f2h(__expf(-u*u));
  }
  return a;
}

// ---------------- prep: frag-linear weight slabs (r7-proven, unchanged) ----------------
__global__ __launch_bounds__(256) void gnn_prep(
    const float* __restrict__ w_up, const float* __restrict__ we_ne,
    const float* __restrict__ embed, const int* __restrict__ atypes,
    u16* __restrict__ wsegs){
  __shared__ u16 lw[16384];
  const int blk = blockIdx.x;          // l*5 + seg
  const int l = blk / 5, seg = blk % 5;
  const int tid = threadIdx.x;
  if (seg < 4){
    const float* src = w_up + (l*512 + seg*128)*128;
#pragma unroll
    for (int mm = 0; mm < 16; mm++){
      int idx = mm*1024 + tid*4;
      float4 v = *(const float4*)(src + idx);
      lw[idx+0] = f2h(v.x); lw[idx+1] = f2h(v.y);
      lw[idx+2] = f2h(v.z); lw[idx+3] = f2h(v.w);
    }
  } else {
#pragma unroll
    for (int mm = 0; mm < 16; mm++){
      int idx = mm*1024 + tid*4;
      int k = idx >> 7, dout = idx & 127;
      int n = k >> 3, f = k & 7;
      float4 ye = *(const float4*)(embed + atypes[n]*128 + dout);
      float4 wn = *(const float4*)(we_ne + (l*8 + f)*128 + dout);
      lw[idx+0] = f2h(ye.x*wn.x); lw[idx+1] = f2h(ye.y*wn.y);
      lw[idx+2] = f2h(ye.z*wn.z); lw[idx+3] = f2h(ye.w*wn.w);
    }
  }
  __syncthreads();
  u16* dst = wsegs + blk*16384;
  const int col = tid & 15, q = (tid >> 4) & 3;
#pragma unroll
  for (int m = 0; m < 8; m++){
    int slot = m*4 + (tid >> 6);
    int c = slot >> 3, nt = slot & 7;
    int kbase = c*32 + q*8;
    int dout = nt*16 + col;
    short8 vv;
#pragma unroll
    for (int jj = 0; jj < 8; jj++) vv[jj] = (short)lw[(kbase+jj)*128 + dout];
    *(short8*)(dst + m*2048 + tid*8) = vv;
  }
}

// ---------------- main ----------------
__global__ __launch_bounds__(256, 2) void gnn_main(
    const float* __restrict__ r_g, const float* __restrict__ R_g,
    const float* __restrict__ weS_g, const float* __restrict__ weA_g,
    const float* __restrict__ bup_g,
    const u16* __restrict__ wsegs,
    float* __restrict__ out)
{
  extern __shared__ __attribute__((aligned(16))) u16 lds[];
  u16* const wb  = lds;                 // 16384 u16 (32 KB), single-buffered
  u16* const xb  = lds + 16384;         // [64][136]
  u16* const zst = lds + 25088;         // [64][136]

  const int tid  = threadIdx.x;
  const int lane = tid & 63;
  const int w    = tid >> 6;            // 0..3 (row-tile within batch)
  const int b    = blockIdx.x;          // one batch per block
  const int col  = lane & 15;
  const int q    = lane >> 4;
  const int i0   = w * 16;
  const int sp   = w >> 1;              // spin group of rows
  const int mrow = i0 + col;
  const int loff = (q*16 + col) * 8;

  u32x4 stg[8];
  auto stg_ld = [&](const u16* src){
#pragma unroll
    for (int m = 0; m < 8; m++) stg[m] = *(const u32x4*)(src + m*2048 + tid*8);
  };
  auto stg_st = [&](u16* dst){
#pragma unroll
    for (int m = 0; m < 8; m++) *(u32x4*)(dst + m*2048 + tid*8) = stg[m];
  };
  // full-seg GEMM: K=128 (4 chunks), N=128 (8 tiles), A from row-major LDS
  auto gemm_seg = [&](const u16* wbuf, const u16* arows, f32x4* acc){
#pragma unroll
    for (int c = 0; c < 4; c++){
      short8 a = *(const short8*)(arows + mrow*136 + c*32 + (q<<3));
#pragma unroll
      for (int nt = 0; nt < 8; nt++){
        short8 bf = *(const short8*)(wbuf + c*4096 + nt*512 + loff);
        acc[nt] = __builtin_amdgcn_mfma_f32_16x16x32_f16(a, bf, acc[nt], 0, 0, 0);
      }
    }
  };

  // ---------------- init: positions, distances, cached A-frags, x init ----------------
  short8 aS[8], aA[8];
  float dN[4];
  {
    float* rs = (float*)zst;             // overlay (dead until first zpass)
    float* Rs = rs + 256;
    if (tid < 64){
#pragma unroll
      for (int k = 0; k < 3; k++) rs[tid*4+k] = r_g[(b*64+tid)*3 + k];
    } else if (tid < 80){
      int n = tid - 64;
#pragma unroll
      for (int k = 0; k < 3; k++) Rs[n*4+k] = R_g[(b*16+n)*3 + k];
    }
    __syncthreads();
    {
      float x0 = rs[mrow*4], x1 = rs[mrow*4+1], x2 = rs[mrow*4+2];
#pragma unroll
      for (int c = 0; c < 8; c++){
        int j = 32*sp + 4*c + q;
        float dx = x0-rs[j*4], dy = x1-rs[j*4+1], dz = x2-rs[j*4+2];
        float dd = sqrtf(dx*dx + dy*dy + dz*dz + 1e-12f);
        aS[c] = rbf8(dd);
        if (j == mrow) aS[c] = (short8)0;          // no self-interaction
        j = 32*(1-sp) + 4*c + q;
        dx = x0-rs[j*4]; dy = x1-rs[j*4+1]; dz = x2-rs[j*4+2];
        aA[c] = rbf8(sqrtf(dx*dx + dy*dy + dz*dz + 1e-12f));
      }
#pragma unroll
      for (int c = 0; c < 4; c++){
        int n = 4*c + q;
        float dx = x0-Rs[n*4], dy = x1-Rs[n*4+1], dz = x2-Rs[n*4+2];
        dN[c] = sqrtf(dx*dx + dy*dy + dz*dz + 1e-12f);
      }
    }
    {
      int i = tid >> 2, nb = (tid & 3)*4;
      float y0 = rs[i*4], y1 = rs[i*4+1], y2 = rs[i*4+2];
#pragma unroll
      for (int nn = 0; nn < 4; nn++){
        int n = nb + nn;
        float dx = y0-Rs[n*4], dy = y1-Rs[n*4+1], dz = y2-Rs[n*4+2];
        float dd = sqrtf(dx*dx + dy*dy + dz*dz + 1e-12f);
        *(short8*)&xb[i*136 + n*8] = rbf8(dd);
      }
    }
    stg_ld(wsegs + 0);          // L0.W0 -> wb
    stg_st(wb);
    __syncthreads();
  }

  f32x4 xr[8];
#pragma unroll
  for (int nt = 0; nt < 8; nt++)
#pragma unroll
    for (int rr = 0; rr < 4; rr++)
      xr[nt][rr] = h2f(xb[(i0 + q*4 + rr)*136 + nt*16 + col]);

  const f32x4 vzero = {0.f, 0.f, 0.f, 0.f};

#pragma unroll 1
  for (int l = 0; l < 3; l++){
    const u16* slab = wsegs + l*81920;

    float bupr[8];
#pragma unroll
    for (int nt = 0; nt < 8; nt++) bupr[nt] = bup_g[l*128 + nt*16 + col];

    f32x4 upd[8];
#pragma unroll
    for (int nt = 0; nt < 8; nt++) upd[nt] = vzero;

    auto zpass = [&](int pass){
      const float* weX = pass ? weA_g : weS_g;
      const int jb0 = pass ? 32*(1-sp) : 32*sp;
      const short8* aF = pass ? aA : aS;
      f32x4 zacc[8];
#pragma unroll
      for (int nt = 0; nt < 8; nt++) zacc[nt] = vzero;
#pragma unroll
      for (int nt = 0; nt < 8; nt++){
        h2 wp[4];
#pragma unroll
        for (int p = 0; p < 4; p++){
          h2 t;
          t[0] = (_Float16)weX[(l*8 + 2*p  )*128 + nt*16 + col];
          t[1] = (_Float16)weX[(l*8 + 2*p+1)*128 + nt*16 + col];
          wp[p] = t;
        }
        u16 xv[8];
#pragma unroll
        for (int c = 0; c < 8; c++) xv[c] = xb[(jb0 + 4*c + q)*136 + nt*16 + col];
#pragma unroll
        for (int c = 0; c < 8; c++){
          _Float16 xh = __builtin_bit_cast(_Float16, xv[c]);
          h2 xd; xd[0] = xh; xd[1] = xh;
          u32x4 bu;
#pragma unroll
          for (int p = 0; p < 4; p++)
            bu[p] = __builtin_bit_cast(u32, (h2)(xd * wp[p]));
          short8 bf = __builtin_bit_cast(short8, bu);
          zacc[nt] = __builtin_amdgcn_mfma_f32_16x16x32_f16(aF[c], bf, zacc[nt], 0, 0, 0);
        }
      }
#pragma unroll
      for (int nt = 0; nt < 8; nt++)
#pragma unroll
        for (int rr = 0; rr < 4; rr++)
          zst[(i0 + q*4 + rr)*136 + nt*16 + col] = f2h(zacc[nt][rr]);
    };

    // ---- t0: consume W0 (x@W0) + zpass(0) | prefetch W1
    stg_ld(slab + 1*16384);
    zpass(0);
    gemm_seg(wb, xb, upd);
    __syncthreads();  stg_st(wb);  __syncthreads();
    // ---- t1: consume W1 (zs@W1) | prefetch W2
    stg_ld(slab + 2*16384);
    gemm_seg(wb, zst, upd);
    __syncthreads();  stg_st(wb);  __syncthreads();
    // ---- t2: zpass(1) then consume W2 (za@W2) | prefetch Y
    stg_ld(slab + 4*16384);
    zpass(1);
    gemm_seg(wb, zst, upd);
    __syncthreads();  stg_st(wb);  __syncthreads();
    // ---- t3: consume Y (zn), write zn->zst | prefetch W3
    stg_ld(slab + 3*16384);
    {
      f32x4 zn[8];
#pragma unroll
      for (int nt = 0; nt < 8; nt++) zn[nt] = vzero;
#pragma unroll
      for (int c = 0; c < 4; c++){
        short8 a = rbf8(dN[c]);
#pragma unroll
        for (int nt = 0; nt < 8; nt++){
          short8 bf = *(const short8*)(wb + c*4096 + nt*512 + loff);
          zn[nt] = __builtin_amdgcn_mfma_f32_16x16x32_f16(a, bf, zn[nt], 0, 0, 0);
        }
      }
#pragma unroll
      for (int nt = 0; nt < 8; nt++)
#pragma unroll
        for (int rr = 0; rr < 4; rr++)
          zst[(i0 + q*4 + rr)*136 + nt*16 + col] = f2h(zn[nt][rr]);
    }
    __syncthreads();  stg_st(wb);  __syncthreads();
    // ---- t4: consume W3 (zn@W3) | prefetch next-layer W0 | epilogue
    if (l < 2) stg_ld(slab + 81920);
    gemm_seg(wb, zst, upd);
#pragma unroll
    for (int nt = 0; nt < 8; nt++){
#pragma unroll
      for (int rr = 0; rr < 4; rr++){
        float v = upd[nt][rr] + bupr[nt];
        float e = __expf(2.0f * v);
        float th = 1.0f - 2.0f * __builtin_amdgcn_rcpf(e + 1.0f);
        xr[nt][rr] += th;
      }
    }
    if (l < 2){
#pragma unroll
      for (int nt = 0; nt < 8; nt++)
#pragma unroll
        for (int rr = 0; rr < 4; rr++)
          xb[(i0 + q*4 + rr)*136 + nt*16 + col] = f2h(xr[nt][rr]);
      __syncthreads();  stg_st(wb);  __syncthreads();
    } else {
#pragma unroll
      for (int nt = 0; nt < 8; nt++)
#pragma unroll
        for (int rr = 0; rr < 4; rr++)
          out[(b*64 + i0 + q*4 + rr)*128 + nt*16 + col] = xr[nt][rr];
    }
  }
}

extern "C" void kernel_launch(void* const* d_in, const int* in_sizes, int n_in,
                              void* d_out, int out_size, void* d_ws, size_t ws_size,
                              hipStream_t stream){
  const float* r     = (const float*)d_in[0];
  const float* R     = (const float*)d_in[1];
  const float* embed = (const float*)d_in[2];
  const float* weS   = (const float*)d_in[3];
  const float* weA   = (const float*)d_in[4];
  const float* weN   = (const float*)d_in[5];
  const float* wup   = (const float*)d_in[6];
  const float* bup   = (const float*)d_in[7];
  const int* atyp    = (const int*)d_in[8];

  u16* wsegs = (u16*)d_ws;                // 3*5*16384 fp16 = 491,520 B (proven size)

  (void)hipFuncSetAttribute((const void*)gnn_main,
                            hipFuncAttributeMaxDynamicSharedMemorySize, 67584);
  gnn_prep<<<15, 256, 0, stream>>>(wup, weN, embed, atyp, wsegs);
  gnn_main<<<512, 256, 67584, stream>>>(r, R, weS, weA, bup, wsegs, (float*)d_out);
}